// Round 1
// baseline (823.256 us; speedup 1.0000x reference)
//
#include <hip/hip_runtime.h>
#include <math.h>

// Problem constants (G, H, C, feature dims fixed by the reference).
static constexpr int G_  = 64;   // graphs
static constexpr int H_  = 4;    // heads
static constexpr int C_  = 64;   // channels per head
static constexpr int IN_ = 260;  // input features
static constexpr int HC_ = 256;  // H_*C_

__device__ __forceinline__ float lrelu02(float x) { return x >= 0.f ? x : 0.2f * x; }
__device__ __forceinline__ float selu_f(float x) {
  const float sc = 1.0507009873554805f, al = 1.6732632423543772f;
  return x > 0.f ? sc * x : sc * al * expm1f(x);
}

// ---------------- CSR build ----------------
__global__ __launch_bounds__(256) void k_count(const int* __restrict__ dst, int* __restrict__ cnt, int E) {
  int e = blockIdx.x * 256 + threadIdx.x;
  if (e < E) atomicAdd(&cnt[dst[e]], 1);
}

__global__ __launch_bounds__(1024) void k_scan(const int* __restrict__ cnt, int* __restrict__ off,
                                               int* __restrict__ cur, int n, int total) {
  __shared__ int wsum[16];
  __shared__ int wpre[16];
  __shared__ int srun;
  int lane = threadIdx.x & 63;
  int wid = threadIdx.x >> 6;
  if (threadIdx.x == 0) srun = 0;
  __syncthreads();
  for (int base = 0; base < n; base += 1024) {
    int i = base + (int)threadIdx.x;
    int v = (i < n) ? cnt[i] : 0;
    int sc = v;
    #pragma unroll
    for (int s = 1; s < 64; s <<= 1) {
      int t = __shfl_up(sc, s, 64);
      if (lane >= s) sc += t;
    }
    if (lane == 63) wsum[wid] = sc;
    __syncthreads();
    if (threadIdx.x == 0) {
      int acc = srun;
      #pragma unroll
      for (int w2 = 0; w2 < 16; w2++) { wpre[w2] = acc; acc += wsum[w2]; }
      srun = acc;
    }
    __syncthreads();
    if (i < n) {
      int excl = wpre[wid] + sc - v;
      off[i] = excl;
      cur[i] = excl;
    }
    __syncthreads();
  }
  if (threadIdx.x == 0) off[n] = total;
}

__global__ __launch_bounds__(256) void k_scatter(const int* __restrict__ src, const int* __restrict__ dst,
                                                 int* __restrict__ cur, int* __restrict__ csr, int E) {
  int e = blockIdx.x * 256 + threadIdx.x;
  if (e < E) {
    int pos = atomicAdd(&cur[dst[e]], 1);
    csr[pos] = src[e];
  }
}

// ---------------- generic fp32 tiled GEMM: C[M,Ncols] = A[M,K] @ B[K,Ncols] ----------------
// MODE 0: plain.  MODE 1: C = selu(A@B + bias)
template <int MODE>
__global__ __launch_bounds__(256) void k_gemm(const float* __restrict__ A, const float* __restrict__ Bm,
                                              const float* __restrict__ bias, float* __restrict__ C,
                                              int M, int K, int Ncols) {
  __shared__ float As[16][68];  // transposed: As[k][m]
  __shared__ float Bs[16][68];
  int bm = blockIdx.x * 64;
  int bn = blockIdx.y * 64;
  int tid = threadIdx.x;
  int tx = tid % 16, ty = tid / 16;
  float acc[4][4] = {};
  for (int kb = 0; kb < K; kb += 16) {
    {  // A tile 64x16 -> transposed
      int row = tid >> 2;
      int c4 = (tid & 3) * 4;
      int gr = bm + row;
      int gc = kb + c4;
      float4 v = make_float4(0.f, 0.f, 0.f, 0.f);
      if (gr < M) {
        if (gc + 3 < K) {
          v = *(const float4*)&A[(size_t)gr * K + gc];
        } else {
          float t[4] = {0.f, 0.f, 0.f, 0.f};
          for (int j = 0; j < 4; j++)
            if (gc + j < K) t[j] = A[(size_t)gr * K + gc + j];
          v = make_float4(t[0], t[1], t[2], t[3]);
        }
      }
      As[c4 + 0][row] = v.x;
      As[c4 + 1][row] = v.y;
      As[c4 + 2][row] = v.z;
      As[c4 + 3][row] = v.w;
    }
    {  // B tile 16x64
      int r = tid >> 4;
      int c = (tid & 15) * 4;
      float4 v = make_float4(0.f, 0.f, 0.f, 0.f);
      if (kb + r < K) v = *(const float4*)&Bm[(size_t)(kb + r) * Ncols + bn + c];
      Bs[r][c + 0] = v.x;
      Bs[r][c + 1] = v.y;
      Bs[r][c + 2] = v.z;
      Bs[r][c + 3] = v.w;
    }
    __syncthreads();
    #pragma unroll
    for (int kk = 0; kk < 16; kk++) {
      const float4 av = *(const float4*)&As[kk][ty * 4];
      const float4 bv = *(const float4*)&Bs[kk][tx * 4];
      float a_[4] = {av.x, av.y, av.z, av.w};
      float b_[4] = {bv.x, bv.y, bv.z, bv.w};
      #pragma unroll
      for (int i = 0; i < 4; i++)
        #pragma unroll
        for (int j = 0; j < 4; j++) acc[i][j] = fmaf(a_[i], b_[j], acc[i][j]);
    }
    __syncthreads();
  }
  #pragma unroll
  for (int i = 0; i < 4; i++) {
    int r = bm + ty * 4 + i;
    if (r < M) {
      float vv[4];
      #pragma unroll
      for (int j = 0; j < 4; j++) {
        float t = acc[i][j];
        if (MODE == 1) t = selu_f(t + bias[bn + tx * 4 + j]);
        vv[j] = t;
      }
      *(float4*)&C[(size_t)r * Ncols + bn + tx * 4] = make_float4(vv[0], vv[1], vv[2], vv[3]);
    }
  }
}

// ---------------- es/ed per node: esed[n][0..3]=es, [4..7]=ed ----------------
__global__ __launch_bounds__(256) void k_esed(const float* __restrict__ h, const float* __restrict__ a_s,
                                              const float* __restrict__ a_d, float* __restrict__ esed, int n) {
  int lane = threadIdx.x & 63;
  int node = blockIdx.x * 4 + (threadIdx.x >> 6);
  if (node >= n) return;
  const float* row = h + (size_t)node * HC_;
  float s[H_], d[H_];
  #pragma unroll
  for (int hh = 0; hh < H_; hh++) {
    float xv = row[hh * C_ + lane];
    s[hh] = xv * a_s[hh * C_ + lane];
    d[hh] = xv * a_d[hh * C_ + lane];
  }
  #pragma unroll
  for (int o2 = 32; o2 > 0; o2 >>= 1) {
    #pragma unroll
    for (int hh = 0; hh < H_; hh++) {
      s[hh] += __shfl_down(s[hh], o2, 64);
      d[hh] += __shfl_down(d[hh], o2, 64);
    }
  }
  if (lane == 0) {
    #pragma unroll
    for (int hh = 0; hh < H_; hh++) {
      esed[(size_t)node * 8 + hh] = s[hh];
      esed[(size_t)node * 8 + 4 + hh] = d[hh];
    }
  }
}

// ---------------- per-dst-node attention aggregation (one wave per node) ----------------
__global__ __launch_bounds__(256) void k_agg(const float* __restrict__ h, const float* __restrict__ esed,
                                             const int* __restrict__ off, const int* __restrict__ csr,
                                             const float* __restrict__ bias, float* __restrict__ out, int n) {
  int lane = threadIdx.x & 63;
  int node = blockIdx.x * 4 + (threadIdx.x >> 6);
  if (node >= n) return;
  int e0 = off[node], e1 = off[node + 1];
  float edn[H_], esn[H_];
  #pragma unroll
  for (int hh = 0; hh < H_; hh++) {
    esn[hh] = esed[(size_t)node * 8 + hh];
    edn[hh] = esed[(size_t)node * 8 + 4 + hh];
  }
  // phase A: per-head max over edges (incl. self-loop)
  float mx[H_];
  #pragma unroll
  for (int hh = 0; hh < H_; hh++) mx[hh] = lrelu02(esn[hh] + edn[hh]);
  for (int k = e0 + lane; k < e1; k += 64) {
    int s = csr[k];
    #pragma unroll
    for (int hh = 0; hh < H_; hh++) {
      float e = lrelu02(esed[(size_t)s * 8 + hh] + edn[hh]);
      mx[hh] = fmaxf(mx[hh], e);
    }
  }
  #pragma unroll
  for (int o2 = 32; o2 > 0; o2 >>= 1)
    #pragma unroll
    for (int hh = 0; hh < H_; hh++) mx[hh] = fmaxf(mx[hh], __shfl_xor(mx[hh], o2, 64));
  // phase B: accumulate exp(e-m)*h[src], denom; divide at end
  float acc[H_] = {0.f, 0.f, 0.f, 0.f};
  float den[H_] = {0.f, 0.f, 0.f, 0.f};
  {
    const float* row = h + (size_t)node * HC_;
    #pragma unroll
    for (int hh = 0; hh < H_; hh++) {
      float ex = __expf(lrelu02(esn[hh] + edn[hh]) - mx[hh]);
      den[hh] += ex;
      acc[hh] = fmaf(ex, row[hh * C_ + lane], acc[hh]);
    }
  }
  for (int k = e0; k < e1; k++) {
    int s = csr[k];
    const float* row = h + (size_t)s * HC_;
    #pragma unroll
    for (int hh = 0; hh < H_; hh++) {
      float ex = __expf(lrelu02(esed[(size_t)s * 8 + hh] + edn[hh]) - mx[hh]);
      den[hh] += ex;
      acc[hh] = fmaf(ex, row[hh * C_ + lane], acc[hh]);
    }
  }
  #pragma unroll
  for (int hh = 0; hh < H_; hh++)
    out[(size_t)node * HC_ + hh * C_ + lane] = acc[hh] / den[hh] + bias[hh * C_ + lane];
}

// ---------------- per-graph mean||max pool (batch sorted) ----------------
__device__ __forceinline__ int lower_bound_i(const int* b, int n, int val) {
  int lo = 0, hi = n;
  while (lo < hi) {
    int mid = (lo + hi) >> 1;
    if (b[mid] < val) lo = mid + 1; else hi = mid;
  }
  return lo;
}

__global__ __launch_bounds__(256) void k_pool(const float* __restrict__ x, const int* __restrict__ batch,
                                              float* __restrict__ out, int n, int colOff) {
  int g = blockIdx.x;
  int start = lower_bound_i(batch, n, g);
  int end = lower_bound_i(batch, n, g + 1);
  int ch = threadIdx.x & 63;
  int sub = threadIdx.x >> 6;
  float sum = 0.f, mx = -INFINITY;
  for (int i = start + sub; i < end; i += 4) {
    float v = x[(size_t)i * C_ + ch];
    sum += v;
    mx = fmaxf(mx, v);
  }
  __shared__ float ssum[4][C_];
  __shared__ float smax[4][C_];
  ssum[sub][ch] = sum;
  smax[sub][ch] = mx;
  __syncthreads();
  if (sub == 0) {
    #pragma unroll
    for (int s2 = 1; s2 < 4; s2++) {
      sum += ssum[s2][ch];
      mx = fmaxf(mx, smax[s2][ch]);
    }
    float cntf = (float)(end - start);
    out[g * 256 + colOff + ch] = sum / cntf;
    out[g * 256 + colOff + C_ + ch] = mx;
  }
}

// ---------------- head MLP + log-softmax + combine (one block per graph) ----------------
__global__ __launch_bounds__(128) void k_head(const float* __restrict__ x1x2, const int* __restrict__ ia,
                                              const float* __restrict__ Ws, const float* __restrict__ bs,
                                              const float* __restrict__ Wsh, const float* __restrict__ bsh,
                                              const float* __restrict__ Wp1, const float* __restrict__ bp1,
                                              const float* __restrict__ Wp2, const float* __restrict__ bp2,
                                              const float* __restrict__ Wp3, const float* __restrict__ bp3,
                                              const float* __restrict__ Wv1, const float* __restrict__ bv1,
                                              const float* __restrict__ Wv2, const float* __restrict__ bv2,
                                              const float* __restrict__ Wv3, const float* __restrict__ bv3,
                                              float* __restrict__ out) {
  int g = blockIdx.x;
  int t = threadIdx.x;
  __shared__ float row[256], t1[128], g2[64], ha[64], hb[64], ha2[64], hb2[64];
  __shared__ float logits[29], lps[5], ens[5];
  row[t] = x1x2[g * 256 + t];
  row[t + 128] = x1x2[g * 256 + 128 + t];
  __syncthreads();
  {  // t1 = row @ Ws + bs (no activation)
    float a = bs[t];
    for (int k = 0; k < 256; k++) a = fmaf(row[k], Ws[k * 128 + t], a);
    t1[t] = a;
  }
  __syncthreads();
  if (t < 64) {
    float a = bsh[t];
    for (int k = 0; k < 128; k++) a = fmaf(t1[k], Wsh[k * 64 + t], a);
    g2[t] = selu_f(a);
  }
  __syncthreads();
  if (t < 64) {
    float a = bp1[t];
    for (int k = 0; k < 64; k++) a = fmaf(g2[k], Wp1[k * 64 + t], a);
    ha[t] = selu_f(a);
  } else {
    int c = t - 64;
    float a = bv1[c];
    for (int k = 0; k < 64; k++) a = fmaf(g2[k], Wv1[k * 64 + c], a);
    hb[c] = selu_f(a);
  }
  __syncthreads();
  if (t < 64) {
    float a = bp2[t];
    for (int k = 0; k < 64; k++) a = fmaf(ha[k], Wp2[k * 64 + t], a);
    ha2[t] = selu_f(a);
  } else {
    int c = t - 64;
    float a = bv2[c];
    for (int k = 0; k < 64; k++) a = fmaf(hb[k], Wv2[k * 64 + c], a);
    hb2[c] = selu_f(a);
  }
  __syncthreads();
  if (t < 29) {
    float a = bp3[t];
    for (int k = 0; k < 64; k++) a = fmaf(ha2[k], Wp3[k * 29 + t], a);
    logits[t] = a;
  }
  if (t == 127) {
    float a = bv3[0];
    for (int k = 0; k < 64; k++) a = fmaf(hb2[k], Wv3[k], a);
    out[128 + g] = a;  // value
  }
  __syncthreads();
  if (t < 5) {
    const int offs[6] = {0, 7, 11, 17, 21, 29};
    int o0 = offs[t], o1 = offs[t + 1];
    float m = -INFINITY;
    for (int j = o0; j < o1; j++) m = fmaxf(m, logits[j]);
    float Z = 0.f;
    for (int j = o0; j < o1; j++) Z += expf(logits[j] - m);
    float lz = logf(Z);
    int act = ia[t * G_ + g];
    lps[t] = logits[o0 + act] - m - lz;
    float ent = 0.f;
    for (int j = o0; j < o1; j++) {
      float lp_ = logits[j] - m - lz;
      ent -= expf(lp_) * lp_;
    }
    ens[t] = ent;
  }
  __syncthreads();
  if (t == 0) {
    int act = ia[g];
    int sel = min(max(act - 1, 0), 4);
    float flp, fen;
    if (act < 3) { flp = lps[1]; fen = ens[1]; }
    else if (act < 5) { flp = lps[sel]; fen = ens[sel]; }
    else if (act == 5) { flp = lps[1] + lps[4]; fen = ens[1] + ens[4]; }
    else { flp = 0.f; fen = 0.f; }
    out[g] = lps[0] + flp;
    out[G_ + g] = ens[0] + fen;
  }
}

extern "C" void kernel_launch(void* const* d_in, const int* in_sizes, int n_in,
                              void* d_out, int out_size, void* d_ws, size_t ws_size,
                              hipStream_t stream) {
  const float* x = (const float*)d_in[0];
  const int* ei = (const int*)d_in[1];
  const int* batch = (const int*)d_in[2];
  const int* ia = (const int*)d_in[3];
  const float* W1 = (const float*)d_in[4];
  const float* as1 = (const float*)d_in[5];
  const float* ad1 = (const float*)d_in[6];
  const float* b1 = (const float*)d_in[7];
  const float* Wl1 = (const float*)d_in[8];
  const float* bl1 = (const float*)d_in[9];
  const float* W2 = (const float*)d_in[10];
  const float* as2 = (const float*)d_in[11];
  const float* ad2 = (const float*)d_in[12];
  const float* b2 = (const float*)d_in[13];
  const float* Wl2 = (const float*)d_in[14];
  const float* bl2 = (const float*)d_in[15];
  const float* Ws = (const float*)d_in[16];
  const float* bs = (const float*)d_in[17];
  const float* Wsh = (const float*)d_in[18];
  const float* bsh = (const float*)d_in[19];
  const float* Wp1 = (const float*)d_in[20];
  const float* bp1 = (const float*)d_in[21];
  const float* Wp2 = (const float*)d_in[22];
  const float* bp2 = (const float*)d_in[23];
  const float* Wp3 = (const float*)d_in[24];
  const float* bp3 = (const float*)d_in[25];
  const float* Wv1 = (const float*)d_in[26];
  const float* bv1 = (const float*)d_in[27];
  const float* Wv2 = (const float*)d_in[28];
  const float* bv2 = (const float*)d_in[29];
  const float* Wv3 = (const float*)d_in[30];
  const float* bv3 = (const float*)d_in[31];
  float* out = (float*)d_out;

  const int n = in_sizes[0] / IN_;
  const int E = in_sizes[1] / 2;
  const int* src = ei;
  const int* dst = ei + E;

  char* w = (char*)d_ws;
  size_t cur_off = 0;
  auto alloc = [&](size_t bytes) -> char* {
    char* p = w + cur_off;
    cur_off = (cur_off + bytes + 255) & ~(size_t)255;
    return p;
  };
  int* cnt = (int*)alloc((size_t)n * 4);
  int* off = (int*)alloc((size_t)(n + 1) * 4);
  int* cur = (int*)alloc((size_t)n * 4);
  int* csr = (int*)alloc((size_t)E * 4);
  float* h = (float*)alloc((size_t)n * HC_ * 4);
  float* esed = (float*)alloc((size_t)n * 8 * 4);
  float* gout = (float*)alloc((size_t)n * HC_ * 4);
  float* hs1 = (float*)alloc((size_t)n * C_ * 4);
  float* hs2 = (float*)alloc((size_t)n * C_ * 4);
  float* x1x2 = (float*)alloc((size_t)G_ * 256 * 4);
  (void)ws_size;
  (void)n_in;
  (void)out_size;

  hipMemsetAsync(cnt, 0, (size_t)n * 4, stream);
  int eb = (E + 255) / 256;
  k_count<<<eb, 256, 0, stream>>>(dst, cnt, E);
  k_scan<<<1, 1024, 0, stream>>>(cnt, off, cur, n, E);
  k_scatter<<<eb, 256, 0, stream>>>(src, dst, cur, csr, E);

  int rt = (n + 63) / 64;
  int nwb = (n + 3) / 4;
  // Layer 1
  k_gemm<0><<<dim3(rt, 4), 256, 0, stream>>>(x, W1, nullptr, h, n, IN_, HC_);
  k_esed<<<nwb, 256, 0, stream>>>(h, as1, ad1, esed, n);
  k_agg<<<nwb, 256, 0, stream>>>(h, esed, off, csr, b1, gout, n);
  k_gemm<1><<<dim3(rt, 1), 256, 0, stream>>>(gout, Wl1, bl1, hs1, n, HC_, C_);
  k_pool<<<G_, 256, 0, stream>>>(hs1, batch, x1x2, n, 0);
  // Layer 2
  k_gemm<0><<<dim3(rt, 4), 256, 0, stream>>>(hs1, W2, nullptr, h, n, C_, HC_);
  k_esed<<<nwb, 256, 0, stream>>>(h, as2, ad2, esed, n);
  k_agg<<<nwb, 256, 0, stream>>>(h, esed, off, csr, b2, gout, n);
  k_gemm<1><<<dim3(rt, 1), 256, 0, stream>>>(gout, Wl2, bl2, hs2, n, HC_, C_);
  k_pool<<<G_, 256, 0, stream>>>(hs2, batch, x1x2, n, 128);
  // Head
  k_head<<<G_, 128, 0, stream>>>(x1x2, ia, Ws, bs, Wsh, bsh, Wp1, bp1, Wp2, bp2, Wp3, bp3,
                                 Wv1, bv1, Wv2, bv2, Wv3, bv3, out);
}

// Round 2
// 703.695 us; speedup vs baseline: 1.1699x; 1.1699x over previous
//
#include <hip/hip_runtime.h>
#include <math.h>

// Problem constants (G, H, C, feature dims fixed by the reference).
static constexpr int G_  = 64;   // graphs
static constexpr int H_  = 4;    // heads
static constexpr int C_  = 64;   // channels per head
static constexpr int IN_ = 260;  // input features
static constexpr int HC_ = 256;  // H_*C_

__device__ __forceinline__ float lrelu02(float x) { return x >= 0.f ? x : 0.2f * x; }
__device__ __forceinline__ float selu_f(float x) {
  const float sc = 1.0507009873554805f, al = 1.6732632423543772f;
  return x > 0.f ? sc * x : sc * al * expm1f(x);
}
__device__ __forceinline__ float bf2f(unsigned short u) {
  return __uint_as_float(((unsigned int)u) << 16);
}
__device__ __forceinline__ unsigned short f2bf(float f) {
  unsigned int u = __float_as_uint(f);
  u = (u + 0x7FFFu + ((u >> 16) & 1u)) >> 16;  // RNE
  return (unsigned short)u;
}

// ---------------- CSR build ----------------
__global__ __launch_bounds__(256) void k_count(const int* __restrict__ dst, int* __restrict__ cnt, int E) {
  int e = blockIdx.x * 256 + threadIdx.x;
  if (e < E) atomicAdd(&cnt[dst[e]], 1);
}

__global__ __launch_bounds__(1024) void k_scan(const int* __restrict__ cnt, int* __restrict__ off,
                                               int* __restrict__ cur, int n, int total) {
  __shared__ int wsum[16];
  __shared__ int wpre[16];
  __shared__ int srun;
  int lane = threadIdx.x & 63;
  int wid = threadIdx.x >> 6;
  if (threadIdx.x == 0) srun = 0;
  __syncthreads();
  for (int base = 0; base < n; base += 1024) {
    int i = base + (int)threadIdx.x;
    int v = (i < n) ? cnt[i] : 0;
    int sc = v;
    #pragma unroll
    for (int s = 1; s < 64; s <<= 1) {
      int t = __shfl_up(sc, s, 64);
      if (lane >= s) sc += t;
    }
    if (lane == 63) wsum[wid] = sc;
    __syncthreads();
    if (threadIdx.x == 0) {
      int acc = srun;
      #pragma unroll
      for (int w2 = 0; w2 < 16; w2++) { wpre[w2] = acc; acc += wsum[w2]; }
      srun = acc;
    }
    __syncthreads();
    if (i < n) {
      int excl = wpre[wid] + sc - v;
      off[i] = excl;
      cur[i] = excl;
    }
    __syncthreads();
  }
  if (threadIdx.x == 0) off[n] = total;
}

__global__ __launch_bounds__(256) void k_scatter(const int* __restrict__ src, const int* __restrict__ dst,
                                                 int* __restrict__ cur, int* __restrict__ csr, int E) {
  int e = blockIdx.x * 256 + threadIdx.x;
  if (e < E) {
    int pos = atomicAdd(&cur[dst[e]], 1);
    csr[pos] = src[e];
  }
}

// ---------------- generic fp32 tiled GEMM: C[M,Ncols] = A[M,K] @ B[K,Ncols] ----------------
// MODE 0: plain, bf16 output.  MODE 1: C = selu(A@B + bias), fp32 output.
template <int MODE>
__global__ __launch_bounds__(256) void k_gemm(const float* __restrict__ A, const float* __restrict__ Bm,
                                              const float* __restrict__ bias, void* __restrict__ Cv,
                                              int M, int K, int Ncols) {
  __shared__ float As[16][68];  // transposed: As[k][m]
  __shared__ float Bs[16][68];
  int bm = blockIdx.x * 64;
  int bn = blockIdx.y * 64;
  int tid = threadIdx.x;
  int tx = tid % 16, ty = tid / 16;
  float acc[4][4] = {};
  for (int kb = 0; kb < K; kb += 16) {
    {  // A tile 64x16 -> transposed
      int row = tid >> 2;
      int c4 = (tid & 3) * 4;
      int gr = bm + row;
      int gc = kb + c4;
      float4 v = make_float4(0.f, 0.f, 0.f, 0.f);
      if (gr < M) {
        if (gc + 3 < K) {
          v = *(const float4*)&A[(size_t)gr * K + gc];
        } else {
          float t[4] = {0.f, 0.f, 0.f, 0.f};
          for (int j = 0; j < 4; j++)
            if (gc + j < K) t[j] = A[(size_t)gr * K + gc + j];
          v = make_float4(t[0], t[1], t[2], t[3]);
        }
      }
      As[c4 + 0][row] = v.x;
      As[c4 + 1][row] = v.y;
      As[c4 + 2][row] = v.z;
      As[c4 + 3][row] = v.w;
    }
    {  // B tile 16x64
      int r = tid >> 4;
      int c = (tid & 15) * 4;
      float4 v = make_float4(0.f, 0.f, 0.f, 0.f);
      if (kb + r < K) v = *(const float4*)&Bm[(size_t)(kb + r) * Ncols + bn + c];
      Bs[r][c + 0] = v.x;
      Bs[r][c + 1] = v.y;
      Bs[r][c + 2] = v.z;
      Bs[r][c + 3] = v.w;
    }
    __syncthreads();
    #pragma unroll
    for (int kk = 0; kk < 16; kk++) {
      const float4 av = *(const float4*)&As[kk][ty * 4];
      const float4 bv = *(const float4*)&Bs[kk][tx * 4];
      float a_[4] = {av.x, av.y, av.z, av.w};
      float b_[4] = {bv.x, bv.y, bv.z, bv.w};
      #pragma unroll
      for (int i = 0; i < 4; i++)
        #pragma unroll
        for (int j = 0; j < 4; j++) acc[i][j] = fmaf(a_[i], b_[j], acc[i][j]);
    }
    __syncthreads();
  }
  #pragma unroll
  for (int i = 0; i < 4; i++) {
    int r = bm + ty * 4 + i;
    if (r < M) {
      if (MODE == 0) {
        unsigned short* C = (unsigned short*)Cv;
        ushort4 pv;
        pv.x = f2bf(acc[i][0]);
        pv.y = f2bf(acc[i][1]);
        pv.z = f2bf(acc[i][2]);
        pv.w = f2bf(acc[i][3]);
        *(ushort4*)&C[(size_t)r * Ncols + bn + tx * 4] = pv;
      } else {
        float* C = (float*)Cv;
        float vv[4];
        #pragma unroll
        for (int j = 0; j < 4; j++) vv[j] = selu_f(acc[i][j] + bias[bn + tx * 4 + j]);
        *(float4*)&C[(size_t)r * Ncols + bn + tx * 4] = make_float4(vv[0], vv[1], vv[2], vv[3]);
      }
    }
  }
}

// ---------------- es/ed per node (bf16 h): esed[n][0..3]=es, [4..7]=ed ----------------
__global__ __launch_bounds__(256) void k_esed(const unsigned short* __restrict__ h, const float* __restrict__ a_s,
                                              const float* __restrict__ a_d, float* __restrict__ esed, int n) {
  int lane = threadIdx.x & 63;
  int node = blockIdx.x * 4 + (threadIdx.x >> 6);
  if (node >= n) return;
  const unsigned short* row = h + (size_t)node * HC_;
  float s[H_], d[H_];
  #pragma unroll
  for (int hh = 0; hh < H_; hh++) {
    float xv = bf2f(row[hh * C_ + lane]);
    s[hh] = xv * a_s[hh * C_ + lane];
    d[hh] = xv * a_d[hh * C_ + lane];
  }
  #pragma unroll
  for (int o2 = 32; o2 > 0; o2 >>= 1) {
    #pragma unroll
    for (int hh = 0; hh < H_; hh++) {
      s[hh] += __shfl_down(s[hh], o2, 64);
      d[hh] += __shfl_down(d[hh], o2, 64);
    }
  }
  if (lane == 0) {
    #pragma unroll
    for (int hh = 0; hh < H_; hh++) {
      esed[(size_t)node * 8 + hh] = s[hh];
      esed[(size_t)node * 8 + 4 + hh] = d[hh];
    }
  }
}

// ---------------- per-dst-node attention aggregation (one wave per node, bf16 h gather) ----------------
__global__ __launch_bounds__(256) void k_agg(const unsigned short* __restrict__ h, const float* __restrict__ esed,
                                             const int* __restrict__ off, const int* __restrict__ csr,
                                             const float* __restrict__ bias, float* __restrict__ out, int n) {
  int lane = threadIdx.x & 63;
  int node = blockIdx.x * 4 + (threadIdx.x >> 6);
  if (node >= n) return;
  int e0 = off[node], e1 = off[node + 1];
  float4 esv = *(const float4*)&esed[(size_t)node * 8];
  float4 edv = *(const float4*)&esed[(size_t)node * 8 + 4];
  const float edn[4] = {edv.x, edv.y, edv.z, edv.w};
  const float eself[4] = {lrelu02(esv.x + edn[0]), lrelu02(esv.y + edn[1]),
                          lrelu02(esv.z + edn[2]), lrelu02(esv.w + edn[3])};
  // phase A: per-head max over edges (incl. self-loop)
  float mx[4] = {eself[0], eself[1], eself[2], eself[3]};
  for (int k = e0 + lane; k < e1; k += 64) {
    int s = csr[k];
    float4 e4 = *(const float4*)&esed[(size_t)s * 8];
    mx[0] = fmaxf(mx[0], lrelu02(e4.x + edn[0]));
    mx[1] = fmaxf(mx[1], lrelu02(e4.y + edn[1]));
    mx[2] = fmaxf(mx[2], lrelu02(e4.z + edn[2]));
    mx[3] = fmaxf(mx[3], lrelu02(e4.w + edn[3]));
  }
  #pragma unroll
  for (int o2 = 32; o2 > 0; o2 >>= 1) {
    #pragma unroll
    for (int hh = 0; hh < 4; hh++) mx[hh] = fmaxf(mx[hh], __shfl_xor(mx[hh], o2, 64));
  }
  // phase B: lane computes weights for its edge in chunk, broadcast via shfl
  float acc[4] = {0.f, 0.f, 0.f, 0.f};
  float den[4] = {0.f, 0.f, 0.f, 0.f};
  for (int base = e0; base < e1; base += 64) {
    int nk = min(64, e1 - base);
    float w0 = 0.f, w1 = 0.f, w2 = 0.f, w3 = 0.f;
    int sid = 0;
    if (lane < nk) {
      int s = csr[base + lane];
      sid = s;
      float4 e4 = *(const float4*)&esed[(size_t)s * 8];
      w0 = __expf(lrelu02(e4.x + edn[0]) - mx[0]);
      w1 = __expf(lrelu02(e4.y + edn[1]) - mx[1]);
      w2 = __expf(lrelu02(e4.z + edn[2]) - mx[2]);
      w3 = __expf(lrelu02(e4.w + edn[3]) - mx[3]);
      den[0] += w0; den[1] += w1; den[2] += w2; den[3] += w3;
    }
    for (int j = 0; j < nk; j++) {
      int s = __shfl(sid, j, 64);
      float a0 = __shfl(w0, j, 64);
      float a1 = __shfl(w1, j, 64);
      float a2 = __shfl(w2, j, 64);
      float a3 = __shfl(w3, j, 64);
      const unsigned short* row = h + (size_t)s * HC_;
      acc[0] = fmaf(a0, bf2f(row[0 * C_ + lane]), acc[0]);
      acc[1] = fmaf(a1, bf2f(row[1 * C_ + lane]), acc[1]);
      acc[2] = fmaf(a2, bf2f(row[2 * C_ + lane]), acc[2]);
      acc[3] = fmaf(a3, bf2f(row[3 * C_ + lane]), acc[3]);
    }
  }
  // reduce den across lanes (each lane has partial from its chunk slots)
  #pragma unroll
  for (int o2 = 32; o2 > 0; o2 >>= 1) {
    #pragma unroll
    for (int hh = 0; hh < 4; hh++) den[hh] += __shfl_xor(den[hh], o2, 64);
  }
  // self-loop contribution
  const unsigned short* srow = h + (size_t)node * HC_;
  #pragma unroll
  for (int hh = 0; hh < 4; hh++) {
    float exs = __expf(eself[hh] - mx[hh]);
    den[hh] += exs;
    acc[hh] = fmaf(exs, bf2f(srow[hh * C_ + lane]), acc[hh]);
    out[(size_t)node * HC_ + hh * C_ + lane] = acc[hh] / den[hh] + bias[hh * C_ + lane];
  }
}

// ---------------- per-graph mean||max pool (batch sorted) ----------------
__device__ __forceinline__ int lower_bound_i(const int* b, int n, int val) {
  int lo = 0, hi = n;
  while (lo < hi) {
    int mid = (lo + hi) >> 1;
    if (b[mid] < val) lo = mid + 1; else hi = mid;
  }
  return lo;
}

__global__ __launch_bounds__(256) void k_pool(const float* __restrict__ x, const int* __restrict__ batch,
                                              float* __restrict__ out, int n, int colOff) {
  int g = blockIdx.x;
  int start = lower_bound_i(batch, n, g);
  int end = lower_bound_i(batch, n, g + 1);
  int ch = threadIdx.x & 63;
  int sub = threadIdx.x >> 6;
  float sum = 0.f, mx = -INFINITY;
  for (int i = start + sub; i < end; i += 4) {
    float v = x[(size_t)i * C_ + ch];
    sum += v;
    mx = fmaxf(mx, v);
  }
  __shared__ float ssum[4][C_];
  __shared__ float smax[4][C_];
  ssum[sub][ch] = sum;
  smax[sub][ch] = mx;
  __syncthreads();
  if (sub == 0) {
    #pragma unroll
    for (int s2 = 1; s2 < 4; s2++) {
      sum += ssum[s2][ch];
      mx = fmaxf(mx, smax[s2][ch]);
    }
    float cntf = (float)(end - start);
    out[g * 256 + colOff + ch] = sum / cntf;
    out[g * 256 + colOff + C_ + ch] = mx;
  }
}

// ---------------- head MLP + log-softmax + combine (one block per graph) ----------------
__global__ __launch_bounds__(128) void k_head(const float* __restrict__ x1x2, const int* __restrict__ ia,
                                              const float* __restrict__ Ws, const float* __restrict__ bs,
                                              const float* __restrict__ Wsh, const float* __restrict__ bsh,
                                              const float* __restrict__ Wp1, const float* __restrict__ bp1,
                                              const float* __restrict__ Wp2, const float* __restrict__ bp2,
                                              const float* __restrict__ Wp3, const float* __restrict__ bp3,
                                              const float* __restrict__ Wv1, const float* __restrict__ bv1,
                                              const float* __restrict__ Wv2, const float* __restrict__ bv2,
                                              const float* __restrict__ Wv3, const float* __restrict__ bv3,
                                              float* __restrict__ out) {
  int g = blockIdx.x;
  int t = threadIdx.x;
  __shared__ float row[256], t1[128], g2[64], ha[64], hb[64], ha2[64], hb2[64];
  __shared__ float logits[29], lps[5], ens[5];
  row[t] = x1x2[g * 256 + t];
  row[t + 128] = x1x2[g * 256 + 128 + t];
  __syncthreads();
  {  // t1 = row @ Ws + bs (no activation)
    float a = bs[t];
    for (int k = 0; k < 256; k++) a = fmaf(row[k], Ws[k * 128 + t], a);
    t1[t] = a;
  }
  __syncthreads();
  if (t < 64) {
    float a = bsh[t];
    for (int k = 0; k < 128; k++) a = fmaf(t1[k], Wsh[k * 64 + t], a);
    g2[t] = selu_f(a);
  }
  __syncthreads();
  if (t < 64) {
    float a = bp1[t];
    for (int k = 0; k < 64; k++) a = fmaf(g2[k], Wp1[k * 64 + t], a);
    ha[t] = selu_f(a);
  } else {
    int c = t - 64;
    float a = bv1[c];
    for (int k = 0; k < 64; k++) a = fmaf(g2[k], Wv1[k * 64 + c], a);
    hb[c] = selu_f(a);
  }
  __syncthreads();
  if (t < 64) {
    float a = bp2[t];
    for (int k = 0; k < 64; k++) a = fmaf(ha[k], Wp2[k * 64 + t], a);
    ha2[t] = selu_f(a);
  } else {
    int c = t - 64;
    float a = bv2[c];
    for (int k = 0; k < 64; k++) a = fmaf(hb[k], Wv2[k * 64 + c], a);
    hb2[c] = selu_f(a);
  }
  __syncthreads();
  if (t < 29) {
    float a = bp3[t];
    for (int k = 0; k < 64; k++) a = fmaf(ha2[k], Wp3[k * 29 + t], a);
    logits[t] = a;
  }
  if (t == 127) {
    float a = bv3[0];
    for (int k = 0; k < 64; k++) a = fmaf(hb2[k], Wv3[k], a);
    out[128 + g] = a;  // value
  }
  __syncthreads();
  if (t < 5) {
    const int offs[6] = {0, 7, 11, 17, 21, 29};
    int o0 = offs[t], o1 = offs[t + 1];
    float m = -INFINITY;
    for (int j = o0; j < o1; j++) m = fmaxf(m, logits[j]);
    float Z = 0.f;
    for (int j = o0; j < o1; j++) Z += expf(logits[j] - m);
    float lz = logf(Z);
    int act = ia[t * G_ + g];
    lps[t] = logits[o0 + act] - m - lz;
    float ent = 0.f;
    for (int j = o0; j < o1; j++) {
      float lp_ = logits[j] - m - lz;
      ent -= expf(lp_) * lp_;
    }
    ens[t] = ent;
  }
  __syncthreads();
  if (t == 0) {
    int act = ia[g];
    int sel = min(max(act - 1, 0), 4);
    float flp, fen;
    if (act < 3) { flp = lps[1]; fen = ens[1]; }
    else if (act < 5) { flp = lps[sel]; fen = ens[sel]; }
    else if (act == 5) { flp = lps[1] + lps[4]; fen = ens[1] + ens[4]; }
    else { flp = 0.f; fen = 0.f; }
    out[g] = lps[0] + flp;
    out[G_ + g] = ens[0] + fen;
  }
}

extern "C" void kernel_launch(void* const* d_in, const int* in_sizes, int n_in,
                              void* d_out, int out_size, void* d_ws, size_t ws_size,
                              hipStream_t stream) {
  const float* x = (const float*)d_in[0];
  const int* ei = (const int*)d_in[1];
  const int* batch = (const int*)d_in[2];
  const int* ia = (const int*)d_in[3];
  const float* W1 = (const float*)d_in[4];
  const float* as1 = (const float*)d_in[5];
  const float* ad1 = (const float*)d_in[6];
  const float* b1 = (const float*)d_in[7];
  const float* Wl1 = (const float*)d_in[8];
  const float* bl1 = (const float*)d_in[9];
  const float* W2 = (const float*)d_in[10];
  const float* as2 = (const float*)d_in[11];
  const float* ad2 = (const float*)d_in[12];
  const float* b2 = (const float*)d_in[13];
  const float* Wl2 = (const float*)d_in[14];
  const float* bl2 = (const float*)d_in[15];
  const float* Ws = (const float*)d_in[16];
  const float* bs = (const float*)d_in[17];
  const float* Wsh = (const float*)d_in[18];
  const float* bsh = (const float*)d_in[19];
  const float* Wp1 = (const float*)d_in[20];
  const float* bp1 = (const float*)d_in[21];
  const float* Wp2 = (const float*)d_in[22];
  const float* bp2 = (const float*)d_in[23];
  const float* Wp3 = (const float*)d_in[24];
  const float* bp3 = (const float*)d_in[25];
  const float* Wv1 = (const float*)d_in[26];
  const float* bv1 = (const float*)d_in[27];
  const float* Wv2 = (const float*)d_in[28];
  const float* bv2 = (const float*)d_in[29];
  const float* Wv3 = (const float*)d_in[30];
  const float* bv3 = (const float*)d_in[31];
  float* out = (float*)d_out;

  const int n = in_sizes[0] / IN_;
  const int E = in_sizes[1] / 2;
  const int* src = ei;
  const int* dst = ei + E;

  char* w = (char*)d_ws;
  size_t cur_off = 0;
  auto alloc = [&](size_t bytes) -> char* {
    char* p = w + cur_off;
    cur_off = (cur_off + bytes + 255) & ~(size_t)255;
    return p;
  };
  int* cnt = (int*)alloc((size_t)n * 4);
  int* off = (int*)alloc((size_t)(n + 1) * 4);
  int* cur = (int*)alloc((size_t)n * 4);
  int* csr = (int*)alloc((size_t)E * 4);
  unsigned short* h = (unsigned short*)alloc((size_t)n * HC_ * 2);  // bf16
  float* esed = (float*)alloc((size_t)n * 8 * 4);
  float* gout = (float*)alloc((size_t)n * HC_ * 4);
  float* hs1 = (float*)alloc((size_t)n * C_ * 4);
  float* hs2 = (float*)alloc((size_t)n * C_ * 4);
  float* x1x2 = (float*)alloc((size_t)G_ * 256 * 4);
  (void)ws_size;
  (void)n_in;
  (void)out_size;

  hipMemsetAsync(cnt, 0, (size_t)n * 4, stream);
  int eb = (E + 255) / 256;
  k_count<<<eb, 256, 0, stream>>>(dst, cnt, E);
  k_scan<<<1, 1024, 0, stream>>>(cnt, off, cur, n, E);
  k_scatter<<<eb, 256, 0, stream>>>(src, dst, cur, csr, E);

  int rt = (n + 63) / 64;
  int nwb = (n + 3) / 4;
  // Layer 1
  k_gemm<0><<<dim3(rt, 4), 256, 0, stream>>>(x, W1, nullptr, h, n, IN_, HC_);
  k_esed<<<nwb, 256, 0, stream>>>(h, as1, ad1, esed, n);
  k_agg<<<nwb, 256, 0, stream>>>(h, esed, off, csr, b1, gout, n);
  k_gemm<1><<<dim3(rt, 1), 256, 0, stream>>>(gout, Wl1, bl1, hs1, n, HC_, C_);
  k_pool<<<G_, 256, 0, stream>>>(hs1, batch, x1x2, n, 0);
  // Layer 2
  k_gemm<0><<<dim3(rt, 4), 256, 0, stream>>>(hs1, W2, nullptr, h, n, C_, HC_);
  k_esed<<<nwb, 256, 0, stream>>>(h, as2, ad2, esed, n);
  k_agg<<<nwb, 256, 0, stream>>>(h, esed, off, csr, b2, gout, n);
  k_gemm<1><<<dim3(rt, 1), 256, 0, stream>>>(gout, Wl2, bl2, hs2, n, HC_, C_);
  k_pool<<<G_, 256, 0, stream>>>(hs2, batch, x1x2, n, 128);
  // Head
  k_head<<<G_, 128, 0, stream>>>(x1x2, ia, Ws, bs, Wsh, bsh, Wp1, bp1, Wp2, bp2, Wp3, bp3,
                                 Wv1, bv1, Wv2, bv2, Wv3, bv3, out);
}

// Round 3
// 567.495 us; speedup vs baseline: 1.4507x; 1.2400x over previous
//
#include <hip/hip_runtime.h>
#include <math.h>

static constexpr int G_  = 64;
static constexpr int H_  = 4;
static constexpr int C_  = 64;
static constexpr int IN_ = 260;
static constexpr int HC_ = 256;

typedef short short8 __attribute__((ext_vector_type(8)));
typedef float f32x4 __attribute__((ext_vector_type(4)));

__device__ __forceinline__ float lrelu02(float x) { return x >= 0.f ? x : 0.2f * x; }
__device__ __forceinline__ float selu_f(float x) {
  const float sc = 1.0507009873554805f, al = 1.6732632423543772f;
  return x > 0.f ? sc * x : sc * al * expm1f(x);
}
__device__ __forceinline__ float bf2f(unsigned short u) {
  return __uint_as_float(((unsigned int)u) << 16);
}
__device__ __forceinline__ unsigned short f2bf(float f) {
  unsigned int u = __float_as_uint(f);
  u = (u + 0x7FFFu + ((u >> 16) & 1u)) >> 16;  // RNE
  return (unsigned short)u;
}

// ---------------- cast + pad x -> bf16 [Mpad][288] ----------------
__global__ __launch_bounds__(256) void k_cast(const float* __restrict__ x, unsigned short* __restrict__ xb,
                                              int n, int Mpad) {
  int idx = blockIdx.x * 256 + threadIdx.x;
  int total = Mpad * 288;
  if (idx >= total) return;
  int r = idx / 288, c = idx - r * 288;
  float v = (r < n && c < IN_) ? x[(size_t)r * IN_ + c] : 0.f;
  xb[idx] = f2bf(v);
}

// ---------------- weight prep: W[K][N] fp32 -> fragment-order bf16 ----------------
// layout: [g][ks][nb][lane][i] ; k = ks*32 + 8*(lane>>4) + i ; n = g*64 + nb*16 + (lane&15)
__global__ __launch_bounds__(256) void k_prep(const float* __restrict__ W, unsigned short* __restrict__ out,
                                              int Kreal, int KS, int N) {
  int pidx = blockIdx.x * 256 + threadIdx.x;
  int total = (N / 64) * KS * 2048;
  if (pidx >= total) return;
  int i = pidx & 7;
  int l = (pidx >> 3) & 63;
  int nb = (pidx >> 9) & 3;
  int ks = (pidx >> 11) % KS;
  int g = (pidx >> 11) / KS;
  int k = ks * 32 + ((l >> 4) << 3) + i;
  int n2 = g * 64 + nb * 16 + (l & 15);
  out[pidx] = (k < Kreal) ? f2bf(W[(size_t)k * N + n2]) : (unsigned short)0;
}

// ---------------- MFMA GEMM: C[Mpad][N] = A[Mpad][Kpad] @ Bprep ----------------
// MODE 0: bf16 out plain. MODE 1: bf16 out selu(x+bias).
// block = 256 thr = 4 waves; block covers 256 rows x 64 cols (col-group = blockIdx.y)
template <int MODE, int KS>
__global__ __launch_bounds__(256) void k_mgemm(const unsigned short* __restrict__ A,
                                               const unsigned short* __restrict__ Bp,
                                               const float* __restrict__ bias,
                                               unsigned short* __restrict__ C,
                                               int Kpad, int N) {
  extern __shared__ char smem[];
  unsigned short* lds = (unsigned short*)smem;
  int tid = threadIdx.x;
  int l = tid & 63;
  int w = tid >> 6;
  int g = blockIdx.y;
  {  // stage B col-slice (fragment-order, straight copy)
    const float4* s = (const float4*)(Bp + (size_t)g * KS * 2048);
    float4* d = (float4*)lds;
    #pragma unroll
    for (int t = 0; t < KS; t++) d[t * 256 + tid] = s[t * 256 + tid];
  }
  __syncthreads();
  int rm = blockIdx.x * 256 + w * 64;
  const unsigned short* arow[4];
  #pragma unroll
  for (int mi = 0; mi < 4; mi++)
    arow[mi] = A + (size_t)(rm + mi * 16 + (l & 15)) * Kpad + ((l >> 4) << 3);
  f32x4 acc[4][4] = {};
  #pragma unroll
  for (int ks = 0; ks < KS; ks++) {
    short8 a[4], b[4];
    #pragma unroll
    for (int mi = 0; mi < 4; mi++) a[mi] = *(const short8*)(arow[mi] + ks * 32);
    #pragma unroll
    for (int nb = 0; nb < 4; nb++) b[nb] = *(const short8*)(lds + (((ks * 4 + nb) * 64) + l) * 8);
    #pragma unroll
    for (int mi = 0; mi < 4; mi++)
      #pragma unroll
      for (int nb = 0; nb < 4; nb++)
        acc[mi][nb] = __builtin_amdgcn_mfma_f32_16x16x32_bf16(a[mi], b[nb], acc[mi][nb], 0, 0, 0);
  }
  int cr = (l >> 4) * 4;
  int cc = l & 15;
  #pragma unroll
  for (int mi = 0; mi < 4; mi++) {
    #pragma unroll
    for (int nb = 0; nb < 4; nb++) {
      int col = g * 64 + nb * 16 + cc;
      float bv = (MODE == 1) ? bias[col] : 0.f;
      #pragma unroll
      for (int r = 0; r < 4; r++) {
        float v = acc[mi][nb][r];
        if (MODE == 1) v = selu_f(v + bv);
        C[(size_t)(rm + mi * 16 + cr + r) * N + col] = f2bf(v);
      }
    }
  }
}

// ---------------- CSR build ----------------
__global__ __launch_bounds__(256) void k_count(const int* __restrict__ dst, int* __restrict__ cnt, int E) {
  int e = blockIdx.x * 256 + threadIdx.x;
  if (e < E) atomicAdd(&cnt[dst[e]], 1);
}

__global__ __launch_bounds__(1024) void k_scan(const int* __restrict__ cnt, int* __restrict__ off,
                                               int* __restrict__ cur, int n, int total) {
  __shared__ int wsum[16];
  __shared__ int wpre[16];
  __shared__ int srun;
  int lane = threadIdx.x & 63;
  int wid = threadIdx.x >> 6;
  if (threadIdx.x == 0) srun = 0;
  __syncthreads();
  for (int base = 0; base < n; base += 1024) {
    int i = base + (int)threadIdx.x;
    int v = (i < n) ? cnt[i] : 0;
    int sc = v;
    #pragma unroll
    for (int s = 1; s < 64; s <<= 1) {
      int t = __shfl_up(sc, s, 64);
      if (lane >= s) sc += t;
    }
    if (lane == 63) wsum[wid] = sc;
    __syncthreads();
    if (threadIdx.x == 0) {
      int acc = srun;
      #pragma unroll
      for (int w2 = 0; w2 < 16; w2++) { wpre[w2] = acc; acc += wsum[w2]; }
      srun = acc;
    }
    __syncthreads();
    if (i < n) {
      int excl = wpre[wid] + sc - v;
      off[i] = excl;
      cur[i] = excl;
    }
    __syncthreads();
  }
  if (threadIdx.x == 0) off[n] = total;
}

__global__ __launch_bounds__(256) void k_scatter(const int* __restrict__ src, const int* __restrict__ dst,
                                                 int* __restrict__ cur, int* __restrict__ csr, int E) {
  int e = blockIdx.x * 256 + threadIdx.x;
  if (e < E) {
    int pos = atomicAdd(&cur[dst[e]], 1);
    csr[pos] = src[e];
  }
}

// ---------------- es/ed per node (bf16 h) ----------------
__global__ __launch_bounds__(256) void k_esed(const unsigned short* __restrict__ h, const float* __restrict__ a_s,
                                              const float* __restrict__ a_d, float* __restrict__ esed, int n) {
  int lane = threadIdx.x & 63;
  int node = blockIdx.x * 4 + (threadIdx.x >> 6);
  if (node >= n) return;
  const unsigned short* row = h + (size_t)node * HC_;
  float s[H_], d[H_];
  #pragma unroll
  for (int hh = 0; hh < H_; hh++) {
    float xv = bf2f(row[hh * C_ + lane]);
    s[hh] = xv * a_s[hh * C_ + lane];
    d[hh] = xv * a_d[hh * C_ + lane];
  }
  #pragma unroll
  for (int o2 = 32; o2 > 0; o2 >>= 1) {
    #pragma unroll
    for (int hh = 0; hh < H_; hh++) {
      s[hh] += __shfl_down(s[hh], o2, 64);
      d[hh] += __shfl_down(d[hh], o2, 64);
    }
  }
  if (lane == 0) {
    #pragma unroll
    for (int hh = 0; hh < H_; hh++) {
      esed[(size_t)node * 8 + hh] = s[hh];
      esed[(size_t)node * 8 + 4 + hh] = d[hh];
    }
  }
}

// ---------------- per-dst-node attention aggregation (bf16 in, bf16 out) ----------------
__global__ __launch_bounds__(256) void k_agg(const unsigned short* __restrict__ h, const float* __restrict__ esed,
                                             const int* __restrict__ off, const int* __restrict__ csr,
                                             const float* __restrict__ bias, unsigned short* __restrict__ out, int n) {
  int lane = threadIdx.x & 63;
  int node = blockIdx.x * 4 + (threadIdx.x >> 6);
  if (node >= n) return;
  int e0 = off[node], e1 = off[node + 1];
  float4 esv = *(const float4*)&esed[(size_t)node * 8];
  float4 edv = *(const float4*)&esed[(size_t)node * 8 + 4];
  const float edn[4] = {edv.x, edv.y, edv.z, edv.w};
  const float eself[4] = {lrelu02(esv.x + edn[0]), lrelu02(esv.y + edn[1]),
                          lrelu02(esv.z + edn[2]), lrelu02(esv.w + edn[3])};
  float mx[4] = {eself[0], eself[1], eself[2], eself[3]};
  for (int k = e0 + lane; k < e1; k += 64) {
    int s = csr[k];
    float4 e4 = *(const float4*)&esed[(size_t)s * 8];
    mx[0] = fmaxf(mx[0], lrelu02(e4.x + edn[0]));
    mx[1] = fmaxf(mx[1], lrelu02(e4.y + edn[1]));
    mx[2] = fmaxf(mx[2], lrelu02(e4.z + edn[2]));
    mx[3] = fmaxf(mx[3], lrelu02(e4.w + edn[3]));
  }
  #pragma unroll
  for (int o2 = 32; o2 > 0; o2 >>= 1) {
    #pragma unroll
    for (int hh = 0; hh < 4; hh++) mx[hh] = fmaxf(mx[hh], __shfl_xor(mx[hh], o2, 64));
  }
  float acc[4] = {0.f, 0.f, 0.f, 0.f};
  float den[4] = {0.f, 0.f, 0.f, 0.f};
  for (int base = e0; base < e1; base += 64) {
    int nk = min(64, e1 - base);
    float w0 = 0.f, w1 = 0.f, w2 = 0.f, w3 = 0.f;
    int sid = 0;
    if (lane < nk) {
      int s = csr[base + lane];
      sid = s;
      float4 e4 = *(const float4*)&esed[(size_t)s * 8];
      w0 = __expf(lrelu02(e4.x + edn[0]) - mx[0]);
      w1 = __expf(lrelu02(e4.y + edn[1]) - mx[1]);
      w2 = __expf(lrelu02(e4.z + edn[2]) - mx[2]);
      w3 = __expf(lrelu02(e4.w + edn[3]) - mx[3]);
      den[0] += w0; den[1] += w1; den[2] += w2; den[3] += w3;
    }
    for (int j = 0; j < nk; j++) {
      int s = __shfl(sid, j, 64);
      float a0 = __shfl(w0, j, 64);
      float a1 = __shfl(w1, j, 64);
      float a2 = __shfl(w2, j, 64);
      float a3 = __shfl(w3, j, 64);
      const unsigned short* row = h + (size_t)s * HC_;
      acc[0] = fmaf(a0, bf2f(row[0 * C_ + lane]), acc[0]);
      acc[1] = fmaf(a1, bf2f(row[1 * C_ + lane]), acc[1]);
      acc[2] = fmaf(a2, bf2f(row[2 * C_ + lane]), acc[2]);
      acc[3] = fmaf(a3, bf2f(row[3 * C_ + lane]), acc[3]);
    }
  }
  #pragma unroll
  for (int o2 = 32; o2 > 0; o2 >>= 1) {
    #pragma unroll
    for (int hh = 0; hh < 4; hh++) den[hh] += __shfl_xor(den[hh], o2, 64);
  }
  const unsigned short* srow = h + (size_t)node * HC_;
  #pragma unroll
  for (int hh = 0; hh < 4; hh++) {
    float exs = __expf(eself[hh] - mx[hh]);
    den[hh] += exs;
    acc[hh] = fmaf(exs, bf2f(srow[hh * C_ + lane]), acc[hh]);
    out[(size_t)node * HC_ + hh * C_ + lane] = f2bf(acc[hh] / den[hh] + bias[hh * C_ + lane]);
  }
}

// ---------------- per-graph mean||max pool (bf16 in, batch sorted) ----------------
__device__ __forceinline__ int lower_bound_i(const int* b, int n, int val) {
  int lo = 0, hi = n;
  while (lo < hi) {
    int mid = (lo + hi) >> 1;
    if (b[mid] < val) lo = mid + 1; else hi = mid;
  }
  return lo;
}

__global__ __launch_bounds__(256) void k_pool(const unsigned short* __restrict__ x, const int* __restrict__ batch,
                                              float* __restrict__ out, int n, int colOff) {
  int g = blockIdx.x;
  int start = lower_bound_i(batch, n, g);
  int end = lower_bound_i(batch, n, g + 1);
  int ch = threadIdx.x & 63;
  int sub = threadIdx.x >> 6;
  float sum = 0.f, mx = -INFINITY;
  for (int i = start + sub; i < end; i += 4) {
    float v = bf2f(x[(size_t)i * C_ + ch]);
    sum += v;
    mx = fmaxf(mx, v);
  }
  __shared__ float ssum[4][C_];
  __shared__ float smax[4][C_];
  ssum[sub][ch] = sum;
  smax[sub][ch] = mx;
  __syncthreads();
  if (sub == 0) {
    #pragma unroll
    for (int s2 = 1; s2 < 4; s2++) {
      sum += ssum[s2][ch];
      mx = fmaxf(mx, smax[s2][ch]);
    }
    float cntf = (float)(end - start);
    out[g * 256 + colOff + ch] = sum / cntf;
    out[g * 256 + colOff + C_ + ch] = mx;
  }
}

// ---------------- head MLP + log-softmax + combine ----------------
__global__ __launch_bounds__(128) void k_head(const float* __restrict__ x1x2, const int* __restrict__ ia,
                                              const float* __restrict__ Ws, const float* __restrict__ bs,
                                              const float* __restrict__ Wsh, const float* __restrict__ bsh,
                                              const float* __restrict__ Wp1, const float* __restrict__ bp1,
                                              const float* __restrict__ Wp2, const float* __restrict__ bp2,
                                              const float* __restrict__ Wp3, const float* __restrict__ bp3,
                                              const float* __restrict__ Wv1, const float* __restrict__ bv1,
                                              const float* __restrict__ Wv2, const float* __restrict__ bv2,
                                              const float* __restrict__ Wv3, const float* __restrict__ bv3,
                                              float* __restrict__ out) {
  int g = blockIdx.x;
  int t = threadIdx.x;
  __shared__ float row[256], t1[128], g2[64], ha[64], hb[64], ha2[64], hb2[64];
  __shared__ float logits[29], lps[5], ens[5];
  row[t] = x1x2[g * 256 + t];
  row[t + 128] = x1x2[g * 256 + 128 + t];
  __syncthreads();
  {
    float a = bs[t];
    for (int k = 0; k < 256; k++) a = fmaf(row[k], Ws[k * 128 + t], a);
    t1[t] = a;
  }
  __syncthreads();
  if (t < 64) {
    float a = bsh[t];
    for (int k = 0; k < 128; k++) a = fmaf(t1[k], Wsh[k * 64 + t], a);
    g2[t] = selu_f(a);
  }
  __syncthreads();
  if (t < 64) {
    float a = bp1[t];
    for (int k = 0; k < 64; k++) a = fmaf(g2[k], Wp1[k * 64 + t], a);
    ha[t] = selu_f(a);
  } else {
    int c = t - 64;
    float a = bv1[c];
    for (int k = 0; k < 64; k++) a = fmaf(g2[k], Wv1[k * 64 + c], a);
    hb[c] = selu_f(a);
  }
  __syncthreads();
  if (t < 64) {
    float a = bp2[t];
    for (int k = 0; k < 64; k++) a = fmaf(ha[k], Wp2[k * 64 + t], a);
    ha2[t] = selu_f(a);
  } else {
    int c = t - 64;
    float a = bv2[c];
    for (int k = 0; k < 64; k++) a = fmaf(hb[k], Wv2[k * 64 + c], a);
    hb2[c] = selu_f(a);
  }
  __syncthreads();
  if (t < 29) {
    float a = bp3[t];
    for (int k = 0; k < 64; k++) a = fmaf(ha2[k], Wp3[k * 29 + t], a);
    logits[t] = a;
  }
  if (t == 127) {
    float a = bv3[0];
    for (int k = 0; k < 64; k++) a = fmaf(hb2[k], Wv3[k], a);
    out[128 + g] = a;
  }
  __syncthreads();
  if (t < 5) {
    const int offs[6] = {0, 7, 11, 17, 21, 29};
    int o0 = offs[t], o1 = offs[t + 1];
    float m = -INFINITY;
    for (int j = o0; j < o1; j++) m = fmaxf(m, logits[j]);
    float Z = 0.f;
    for (int j = o0; j < o1; j++) Z += expf(logits[j] - m);
    float lz = logf(Z);
    int act = ia[t * G_ + g];
    lps[t] = logits[o0 + act] - m - lz;
    float ent = 0.f;
    for (int j = o0; j < o1; j++) {
      float lp_ = logits[j] - m - lz;
      ent -= expf(lp_) * lp_;
    }
    ens[t] = ent;
  }
  __syncthreads();
  if (t == 0) {
    int act = ia[g];
    int sel = min(max(act - 1, 0), 4);
    float flp, fen;
    if (act < 3) { flp = lps[1]; fen = ens[1]; }
    else if (act < 5) { flp = lps[sel]; fen = ens[sel]; }
    else if (act == 5) { flp = lps[1] + lps[4]; fen = ens[1] + ens[4]; }
    else { flp = 0.f; fen = 0.f; }
    out[g] = lps[0] + flp;
    out[G_ + g] = ens[0] + fen;
  }
}

extern "C" void kernel_launch(void* const* d_in, const int* in_sizes, int n_in,
                              void* d_out, int out_size, void* d_ws, size_t ws_size,
                              hipStream_t stream) {
  const float* x = (const float*)d_in[0];
  const int* ei = (const int*)d_in[1];
  const int* batch = (const int*)d_in[2];
  const int* ia = (const int*)d_in[3];
  const float* W1 = (const float*)d_in[4];
  const float* as1 = (const float*)d_in[5];
  const float* ad1 = (const float*)d_in[6];
  const float* b1 = (const float*)d_in[7];
  const float* Wl1 = (const float*)d_in[8];
  const float* bl1 = (const float*)d_in[9];
  const float* W2 = (const float*)d_in[10];
  const float* as2 = (const float*)d_in[11];
  const float* ad2 = (const float*)d_in[12];
  const float* b2 = (const float*)d_in[13];
  const float* Wl2 = (const float*)d_in[14];
  const float* bl2 = (const float*)d_in[15];
  const float* Ws = (const float*)d_in[16];
  const float* bs = (const float*)d_in[17];
  const float* Wsh = (const float*)d_in[18];
  const float* bsh = (const float*)d_in[19];
  const float* Wp1 = (const float*)d_in[20];
  const float* bp1 = (const float*)d_in[21];
  const float* Wp2 = (const float*)d_in[22];
  const float* bp2 = (const float*)d_in[23];
  const float* Wp3 = (const float*)d_in[24];
  const float* bp3 = (const float*)d_in[25];
  const float* Wv1 = (const float*)d_in[26];
  const float* bv1 = (const float*)d_in[27];
  const float* Wv2 = (const float*)d_in[28];
  const float* bv2 = (const float*)d_in[29];
  const float* Wv3 = (const float*)d_in[30];
  const float* bv3 = (const float*)d_in[31];
  float* out = (float*)d_out;

  const int n = in_sizes[0] / IN_;
  const int E = in_sizes[1] / 2;
  const int Mpad = ((n + 255) / 256) * 256;
  const int* src = ei;
  const int* dst = ei + E;

  char* w = (char*)d_ws;
  size_t cur_off = 0;
  auto alloc = [&](size_t bytes) -> char* {
    char* p = w + cur_off;
    cur_off = (cur_off + bytes + 255) & ~(size_t)255;
    return p;
  };
  int* cnt = (int*)alloc((size_t)n * 4);
  int* off = (int*)alloc((size_t)(n + 1) * 4);
  int* cur = (int*)alloc((size_t)n * 4);
  int* csr = (int*)alloc((size_t)E * 4);
  unsigned short* xb = (unsigned short*)alloc((size_t)Mpad * 288 * 2);
  unsigned short* h = (unsigned short*)alloc((size_t)Mpad * HC_ * 2);
  float* esed = (float*)alloc((size_t)n * 8 * 4);
  unsigned short* gout = (unsigned short*)alloc((size_t)Mpad * HC_ * 2);
  unsigned short* hs1 = (unsigned short*)alloc((size_t)Mpad * C_ * 2);
  unsigned short* hs2 = (unsigned short*)alloc((size_t)Mpad * C_ * 2);
  unsigned short* W1p = (unsigned short*)alloc((size_t)4 * 9 * 2048 * 2);
  unsigned short* W2p = (unsigned short*)alloc((size_t)4 * 2 * 2048 * 2);
  unsigned short* Wl1p = (unsigned short*)alloc((size_t)1 * 8 * 2048 * 2);
  unsigned short* Wl2p = (unsigned short*)alloc((size_t)1 * 8 * 2048 * 2);
  float* x1x2 = (float*)alloc((size_t)G_ * 256 * 4);
  (void)ws_size;
  (void)n_in;
  (void)out_size;

  // prep: cast x, pack weights, build CSR
  k_cast<<<(Mpad * 288 + 255) / 256, 256, 0, stream>>>(x, xb, n, Mpad);
  k_prep<<<(4 * 9 * 2048 + 255) / 256, 256, 0, stream>>>(W1, W1p, IN_, 9, HC_);
  k_prep<<<(4 * 2 * 2048 + 255) / 256, 256, 0, stream>>>(W2, W2p, C_, 2, HC_);
  k_prep<<<(1 * 8 * 2048 + 255) / 256, 256, 0, stream>>>(Wl1, Wl1p, HC_, 8, C_);
  k_prep<<<(1 * 8 * 2048 + 255) / 256, 256, 0, stream>>>(Wl2, Wl2p, HC_, 8, C_);
  hipMemsetAsync(cnt, 0, (size_t)n * 4, stream);
  int eb = (E + 255) / 256;
  k_count<<<eb, 256, 0, stream>>>(dst, cnt, E);
  k_scan<<<1, 1024, 0, stream>>>(cnt, off, cur, n, E);
  k_scatter<<<eb, 256, 0, stream>>>(src, dst, cur, csr, E);

  int gx = Mpad / 256;
  int nwb = (n + 3) / 4;
  // Layer 1
  k_mgemm<0, 9><<<dim3(gx, 4), 256, 9 * 4096, stream>>>(xb, W1p, nullptr, h, 288, HC_);
  k_esed<<<nwb, 256, 0, stream>>>(h, as1, ad1, esed, n);
  k_agg<<<nwb, 256, 0, stream>>>(h, esed, off, csr, b1, gout, n);
  k_mgemm<1, 8><<<dim3(gx, 1), 256, 8 * 4096, stream>>>(gout, Wl1p, bl1, hs1, HC_, C_);
  k_pool<<<G_, 256, 0, stream>>>(hs1, batch, x1x2, n, 0);
  // Layer 2
  k_mgemm<0, 2><<<dim3(gx, 4), 256, 2 * 4096, stream>>>(hs1, W2p, nullptr, h, C_, HC_);
  k_esed<<<nwb, 256, 0, stream>>>(h, as2, ad2, esed, n);
  k_agg<<<nwb, 256, 0, stream>>>(h, esed, off, csr, b2, gout, n);
  k_mgemm<1, 8><<<dim3(gx, 1), 256, 8 * 4096, stream>>>(gout, Wl2p, bl2, hs2, HC_, C_);
  k_pool<<<G_, 256, 0, stream>>>(hs2, batch, x1x2, n, 128);
  // Head
  k_head<<<G_, 128, 0, stream>>>(x1x2, ia, Ws, bs, Wsh, bsh, Wp1, bp1, Wp2, bp2, Wp3, bp3,
                                 Wv1, bv1, Wv2, bv2, Wv3, bv3, out);
}

// Round 4
// 543.893 us; speedup vs baseline: 1.5136x; 1.0434x over previous
//
#include <hip/hip_runtime.h>
#include <math.h>

static constexpr int G_  = 64;
static constexpr int H_  = 4;
static constexpr int C_  = 64;
static constexpr int IN_ = 260;
static constexpr int HC_ = 256;

typedef short short8 __attribute__((ext_vector_type(8)));
typedef float f32x4 __attribute__((ext_vector_type(4)));

__device__ __forceinline__ float lrelu02(float x) { return x >= 0.f ? x : 0.2f * x; }
__device__ __forceinline__ float selu_f(float x) {
  const float sc = 1.0507009873554805f, al = 1.6732632423543772f;
  return x > 0.f ? sc * x : sc * al * expm1f(x);
}
__device__ __forceinline__ float bf2f(unsigned short u) {
  return __uint_as_float(((unsigned int)u) << 16);
}
__device__ __forceinline__ unsigned short f2bf(float f) {
  unsigned int u = __float_as_uint(f);
  u = (u + 0x7FFFu + ((u >> 16) & 1u)) >> 16;  // RNE
  return (unsigned short)u;
}

// ---------------- cast + pad x -> bf16 [Mpad][288] ----------------
__global__ __launch_bounds__(256) void k_cast(const float* __restrict__ x, unsigned short* __restrict__ xb,
                                              int n, int Mpad) {
  int idx = blockIdx.x * 256 + threadIdx.x;
  int total = Mpad * 288;
  if (idx >= total) return;
  int r = idx / 288, c = idx - r * 288;
  float v = (r < n && c < IN_) ? x[(size_t)r * IN_ + c] : 0.f;
  xb[idx] = f2bf(v);
}

// ---------------- weight prep: W[K][N] fp32 -> fragment-order bf16 ----------------
// layout: [g][ks][nb][lane][i] ; k = ks*32 + 8*(lane>>4) + i ; n = g*64 + nb*16 + (lane&15)
__global__ __launch_bounds__(256) void k_prep(const float* __restrict__ W, unsigned short* __restrict__ out,
                                              int Kreal, int KS, int N) {
  int pidx = blockIdx.x * 256 + threadIdx.x;
  int total = (N / 64) * KS * 2048;
  if (pidx >= total) return;
  int i = pidx & 7;
  int l = (pidx >> 3) & 63;
  int nb = (pidx >> 9) & 3;
  int ks = (pidx >> 11) % KS;
  int g = (pidx >> 11) / KS;
  int k = ks * 32 + ((l >> 4) << 3) + i;
  int n2 = g * 64 + nb * 16 + (l & 15);
  out[pidx] = (k < Kreal) ? f2bf(W[(size_t)k * N + n2]) : (unsigned short)0;
}

// ---------------- MFMA GEMM ----------------
// MODE 0: bf16 out plain. MODE 1: bf16 out selu(x+bias).
// PERM 1: store col permuted -> [row][ (col&63)*4 + (col>>6) ]  (head-interleaved)
template <int MODE, int KS, int PERM>
__global__ __launch_bounds__(256) void k_mgemm(const unsigned short* __restrict__ A,
                                               const unsigned short* __restrict__ Bp,
                                               const float* __restrict__ bias,
                                               unsigned short* __restrict__ C,
                                               int Kpad, int N) {
  extern __shared__ char smem[];
  unsigned short* lds = (unsigned short*)smem;
  int tid = threadIdx.x;
  int l = tid & 63;
  int w = tid >> 6;
  int g = blockIdx.y;
  {
    const float4* s = (const float4*)(Bp + (size_t)g * KS * 2048);
    float4* d = (float4*)lds;
    #pragma unroll
    for (int t = 0; t < KS; t++) d[t * 256 + tid] = s[t * 256 + tid];
  }
  __syncthreads();
  int rm = blockIdx.x * 256 + w * 64;
  const unsigned short* arow[4];
  #pragma unroll
  for (int mi = 0; mi < 4; mi++)
    arow[mi] = A + (size_t)(rm + mi * 16 + (l & 15)) * Kpad + ((l >> 4) << 3);
  f32x4 acc[4][4] = {};
  #pragma unroll
  for (int ks = 0; ks < KS; ks++) {
    short8 a[4], b[4];
    #pragma unroll
    for (int mi = 0; mi < 4; mi++) a[mi] = *(const short8*)(arow[mi] + ks * 32);
    #pragma unroll
    for (int nb = 0; nb < 4; nb++) b[nb] = *(const short8*)(lds + (((ks * 4 + nb) * 64) + l) * 8);
    #pragma unroll
    for (int mi = 0; mi < 4; mi++)
      #pragma unroll
      for (int nb = 0; nb < 4; nb++)
        acc[mi][nb] = __builtin_amdgcn_mfma_f32_16x16x32_bf16(a[mi], b[nb], acc[mi][nb], 0, 0, 0);
  }
  int cr = (l >> 4) * 4;
  int cc = l & 15;
  #pragma unroll
  for (int mi = 0; mi < 4; mi++) {
    #pragma unroll
    for (int nb = 0; nb < 4; nb++) {
      int col = g * 64 + nb * 16 + cc;
      float bv = (MODE == 1) ? bias[col] : 0.f;
      int colp = PERM ? ((col & 63) * 4 + (col >> 6)) : col;
      #pragma unroll
      for (int r = 0; r < 4; r++) {
        float v = acc[mi][nb][r];
        if (MODE == 1) v = selu_f(v + bv);
        C[(size_t)(rm + mi * 16 + cr + r) * N + colp] = f2bf(v);
      }
    }
  }
}

// ---------------- CSR build ----------------
__global__ __launch_bounds__(256) void k_count(const int* __restrict__ dst, int* __restrict__ cnt, int E) {
  int e = blockIdx.x * 256 + threadIdx.x;
  if (e < E) atomicAdd(&cnt[dst[e]], 1);
}

// hierarchical scan: block sums -> 1-wave scan -> per-block offsets
__global__ __launch_bounds__(256) void k_bsum(const int* __restrict__ cnt, int* __restrict__ bsum, int n) {
  int b = blockIdx.x, tid = threadIdx.x;
  int i0 = b * 1024 + tid * 4;
  int s = 0;
  #pragma unroll
  for (int j = 0; j < 4; j++)
    if (i0 + j < n) s += cnt[i0 + j];
  #pragma unroll
  for (int o = 32; o > 0; o >>= 1) s += __shfl_xor(s, o, 64);
  __shared__ int ws_[4];
  if ((tid & 63) == 0) ws_[tid >> 6] = s;
  __syncthreads();
  if (tid == 0) bsum[b] = ws_[0] + ws_[1] + ws_[2] + ws_[3];
}

__global__ __launch_bounds__(64) void k_bscan(int* __restrict__ bsum, int nb, int* __restrict__ off,
                                              int n, int total) {
  int lane = threadIdx.x;
  int carry = 0;
  for (int base = 0; base < nb; base += 64) {
    int v = (base + lane < nb) ? bsum[base + lane] : 0;
    int sc = v;
    #pragma unroll
    for (int s = 1; s < 64; s <<= 1) {
      int t = __shfl_up(sc, s, 64);
      if (lane >= s) sc += t;
    }
    if (base + lane < nb) bsum[base + lane] = carry + sc - v;
    carry += __shfl(sc, 63, 64);
  }
  if (lane == 0) off[n] = total;
}

__global__ __launch_bounds__(256) void k_boff(const int* __restrict__ cnt, const int* __restrict__ bpre,
                                              int* __restrict__ off, int* __restrict__ cur, int n) {
  int b = blockIdx.x, tid = threadIdx.x;
  int lane = tid & 63, w = tid >> 6;
  int i0 = b * 1024 + tid * 4;
  int v[4];
  #pragma unroll
  for (int j = 0; j < 4; j++) v[j] = (i0 + j < n) ? cnt[i0 + j] : 0;
  int ts = v[0] + v[1] + v[2] + v[3];
  int sc = ts;
  #pragma unroll
  for (int s = 1; s < 64; s <<= 1) {
    int t = __shfl_up(sc, s, 64);
    if (lane >= s) sc += t;
  }
  __shared__ int wsum[4], wpre[4];
  if (lane == 63) wsum[w] = sc;
  __syncthreads();
  if (tid == 0) {
    int a = 0;
    #pragma unroll
    for (int k = 0; k < 4; k++) { wpre[k] = a; a += wsum[k]; }
  }
  __syncthreads();
  int excl = bpre[b] + wpre[w] + sc - ts;
  #pragma unroll
  for (int j = 0; j < 4; j++) {
    if (i0 + j < n) { off[i0 + j] = excl; cur[i0 + j] = excl; }
    excl += v[j];
  }
}

__global__ __launch_bounds__(256) void k_scatter(const int* __restrict__ src, const int* __restrict__ dst,
                                                 int* __restrict__ cur, int* __restrict__ csr, int E) {
  int e = blockIdx.x * 256 + threadIdx.x;
  if (e < E) {
    int pos = atomicAdd(&cur[dst[e]], 1);
    csr[pos] = src[e];
  }
}

// ---------------- es/ed per node (h permuted [node][c][hh]) ----------------
__global__ __launch_bounds__(256) void k_esed(const unsigned short* __restrict__ h, const float* __restrict__ a_s,
                                              const float* __restrict__ a_d, float* __restrict__ esed, int n) {
  int lane = threadIdx.x & 63;
  int node = blockIdx.x * 4 + (threadIdx.x >> 6);
  if (node >= n) return;
  ushort4 u = *(const ushort4*)(h + (size_t)node * HC_ + lane * 4);
  float xv[4] = {bf2f(u.x), bf2f(u.y), bf2f(u.z), bf2f(u.w)};
  float s[H_], d[H_];
  #pragma unroll
  for (int hh = 0; hh < H_; hh++) {
    s[hh] = xv[hh] * a_s[hh * C_ + lane];
    d[hh] = xv[hh] * a_d[hh * C_ + lane];
  }
  #pragma unroll
  for (int o2 = 32; o2 > 0; o2 >>= 1) {
    #pragma unroll
    for (int hh = 0; hh < H_; hh++) {
      s[hh] += __shfl_down(s[hh], o2, 64);
      d[hh] += __shfl_down(d[hh], o2, 64);
    }
  }
  if (lane == 0) {
    #pragma unroll
    for (int hh = 0; hh < H_; hh++) {
      esed[(size_t)node * 8 + hh] = s[hh];
      esed[(size_t)node * 8 + 4 + hh] = d[hh];
    }
  }
}

// ---------------- per-dst-node online-softmax aggregation ----------------
// h permuted [node][c][hh]; out standard [node][hh*64+c] (bf16)
__global__ __launch_bounds__(256) void k_agg(const unsigned short* __restrict__ h, const float* __restrict__ esed,
                                             const int* __restrict__ off, const int* __restrict__ csr,
                                             const float* __restrict__ bias, unsigned short* __restrict__ out, int n) {
  __shared__ float4 wlds[4][64];
  __shared__ int slds[4][64];
  int lane = threadIdx.x & 63;
  int wv = threadIdx.x >> 6;
  int node = blockIdx.x * 4 + wv;
  if (node >= n) return;
  int e0 = off[node], e1 = off[node + 1];
  const float4 esv = ((const float4*)esed)[(size_t)node * 2];
  const float4 edv = ((const float4*)esed)[(size_t)node * 2 + 1];
  const float edn[4] = {edv.x, edv.y, edv.z, edv.w};
  const float eself[4] = {lrelu02(esv.x + edn[0]), lrelu02(esv.y + edn[1]),
                          lrelu02(esv.z + edn[2]), lrelu02(esv.w + edn[3])};
  float m[4] = {eself[0], eself[1], eself[2], eself[3]};
  float acc[4] = {0.f, 0.f, 0.f, 0.f};
  float den[4] = {0.f, 0.f, 0.f, 0.f};
  for (int base = e0; base < e1; base += 64) {
    int nk = min(64, e1 - base);
    float e4[4];
    int sid = 0;
    if (lane < nk) {
      sid = csr[base + lane];
      float4 q = ((const float4*)esed)[(size_t)sid * 2];
      e4[0] = lrelu02(q.x + edn[0]);
      e4[1] = lrelu02(q.y + edn[1]);
      e4[2] = lrelu02(q.z + edn[2]);
      e4[3] = lrelu02(q.w + edn[3]);
    } else {
      e4[0] = e4[1] = e4[2] = e4[3] = -INFINITY;
    }
    // chunk max (all lanes)
    float cm[4] = {e4[0], e4[1], e4[2], e4[3]};
    #pragma unroll
    for (int o2 = 32; o2 > 0; o2 >>= 1) {
      #pragma unroll
      for (int hh = 0; hh < 4; hh++) cm[hh] = fmaxf(cm[hh], __shfl_xor(cm[hh], o2, 64));
    }
    // online rescale
    #pragma unroll
    for (int hh = 0; hh < 4; hh++) {
      float nm = fmaxf(m[hh], cm[hh]);
      float sc = __expf(m[hh] - nm);
      acc[hh] *= sc;
      den[hh] *= sc;
      m[hh] = nm;
    }
    // per-lane weights -> LDS
    float4 w4 = make_float4(0.f, 0.f, 0.f, 0.f);
    if (lane < nk) {
      w4.x = __expf(e4[0] - m[0]);
      w4.y = __expf(e4[1] - m[1]);
      w4.z = __expf(e4[2] - m[2]);
      w4.w = __expf(e4[3] - m[3]);
      den[0] += w4.x; den[1] += w4.y; den[2] += w4.z; den[3] += w4.w;
    }
    wlds[wv][lane] = w4;
    slds[wv][lane] = sid;
    // accumulate (broadcast ds reads, unrolled x4 for load ILP)
    int j = 0;
    for (; j + 4 <= nk; j += 4) {
      float4 wa = wlds[wv][j], wb = wlds[wv][j + 1], wc = wlds[wv][j + 2], wd = wlds[wv][j + 3];
      int sa = slds[wv][j], sb = slds[wv][j + 1], sc2 = slds[wv][j + 2], sd = slds[wv][j + 3];
      ushort4 ua = *(const ushort4*)(h + (size_t)sa * HC_ + lane * 4);
      ushort4 ub = *(const ushort4*)(h + (size_t)sb * HC_ + lane * 4);
      ushort4 uc = *(const ushort4*)(h + (size_t)sc2 * HC_ + lane * 4);
      ushort4 ud = *(const ushort4*)(h + (size_t)sd * HC_ + lane * 4);
      acc[0] = fmaf(wa.x, bf2f(ua.x), acc[0]);
      acc[1] = fmaf(wa.y, bf2f(ua.y), acc[1]);
      acc[2] = fmaf(wa.z, bf2f(ua.z), acc[2]);
      acc[3] = fmaf(wa.w, bf2f(ua.w), acc[3]);
      acc[0] = fmaf(wb.x, bf2f(ub.x), acc[0]);
      acc[1] = fmaf(wb.y, bf2f(ub.y), acc[1]);
      acc[2] = fmaf(wb.z, bf2f(ub.z), acc[2]);
      acc[3] = fmaf(wb.w, bf2f(ub.w), acc[3]);
      acc[0] = fmaf(wc.x, bf2f(uc.x), acc[0]);
      acc[1] = fmaf(wc.y, bf2f(uc.y), acc[1]);
      acc[2] = fmaf(wc.z, bf2f(uc.z), acc[2]);
      acc[3] = fmaf(wc.w, bf2f(uc.w), acc[3]);
      acc[0] = fmaf(wd.x, bf2f(ud.x), acc[0]);
      acc[1] = fmaf(wd.y, bf2f(ud.y), acc[1]);
      acc[2] = fmaf(wd.z, bf2f(ud.z), acc[2]);
      acc[3] = fmaf(wd.w, bf2f(ud.w), acc[3]);
    }
    for (; j < nk; j++) {
      float4 wj = wlds[wv][j];
      int s = slds[wv][j];
      ushort4 u = *(const ushort4*)(h + (size_t)s * HC_ + lane * 4);
      acc[0] = fmaf(wj.x, bf2f(u.x), acc[0]);
      acc[1] = fmaf(wj.y, bf2f(u.y), acc[1]);
      acc[2] = fmaf(wj.z, bf2f(u.z), acc[2]);
      acc[3] = fmaf(wj.w, bf2f(u.w), acc[3]);
    }
  }
  // reduce den across lanes
  #pragma unroll
  for (int o2 = 32; o2 > 0; o2 >>= 1) {
    #pragma unroll
    for (int hh = 0; hh < 4; hh++) den[hh] += __shfl_xor(den[hh], o2, 64);
  }
  // self-loop
  ushort4 us = *(const ushort4*)(h + (size_t)node * HC_ + lane * 4);
  float uv[4] = {bf2f(us.x), bf2f(us.y), bf2f(us.z), bf2f(us.w)};
  #pragma unroll
  for (int hh = 0; hh < 4; hh++) {
    float exs = __expf(eself[hh] - m[hh]);
    den[hh] += exs;
    acc[hh] = fmaf(exs, uv[hh], acc[hh]);
    out[(size_t)node * HC_ + hh * C_ + lane] = f2bf(acc[hh] / den[hh] + bias[hh * C_ + lane]);
  }
}

// ---------------- per-graph mean||max pool (bf16 in, batch sorted) ----------------
__device__ __forceinline__ int lower_bound_i(const int* b, int n, int val) {
  int lo = 0, hi = n;
  while (lo < hi) {
    int mid = (lo + hi) >> 1;
    if (b[mid] < val) lo = mid + 1; else hi = mid;
  }
  return lo;
}

__global__ __launch_bounds__(256) void k_pool(const unsigned short* __restrict__ x, const int* __restrict__ batch,
                                              float* __restrict__ out, int n, int colOff) {
  int g = blockIdx.x;
  int start = lower_bound_i(batch, n, g);
  int end = lower_bound_i(batch, n, g + 1);
  int ch = threadIdx.x & 63;
  int sub = threadIdx.x >> 6;
  float sum = 0.f, mx = -INFINITY;
  for (int i = start + sub; i < end; i += 4) {
    float v = bf2f(x[(size_t)i * C_ + ch]);
    sum += v;
    mx = fmaxf(mx, v);
  }
  __shared__ float ssum[4][C_];
  __shared__ float smax[4][C_];
  ssum[sub][ch] = sum;
  smax[sub][ch] = mx;
  __syncthreads();
  if (sub == 0) {
    #pragma unroll
    for (int s2 = 1; s2 < 4; s2++) {
      sum += ssum[s2][ch];
      mx = fmaxf(mx, smax[s2][ch]);
    }
    float cntf = (float)(end - start);
    out[g * 256 + colOff + ch] = sum / cntf;
    out[g * 256 + colOff + C_ + ch] = mx;
  }
}

// ---------------- head MLP + log-softmax + combine ----------------
__global__ __launch_bounds__(128) void k_head(const float* __restrict__ x1x2, const int* __restrict__ ia,
                                              const float* __restrict__ Ws, const float* __restrict__ bs,
                                              const float* __restrict__ Wsh, const float* __restrict__ bsh,
                                              const float* __restrict__ Wp1, const float* __restrict__ bp1,
                                              const float* __restrict__ Wp2, const float* __restrict__ bp2,
                                              const float* __restrict__ Wp3, const float* __restrict__ bp3,
                                              const float* __restrict__ Wv1, const float* __restrict__ bv1,
                                              const float* __restrict__ Wv2, const float* __restrict__ bv2,
                                              const float* __restrict__ Wv3, const float* __restrict__ bv3,
                                              float* __restrict__ out) {
  int g = blockIdx.x;
  int t = threadIdx.x;
  __shared__ float row[256], t1[128], g2[64], ha[64], hb[64], ha2[64], hb2[64];
  __shared__ float logits[29], lps[5], ens[5];
  row[t] = x1x2[g * 256 + t];
  row[t + 128] = x1x2[g * 256 + 128 + t];
  __syncthreads();
  {
    float a = bs[t];
    for (int k = 0; k < 256; k++) a = fmaf(row[k], Ws[k * 128 + t], a);
    t1[t] = a;
  }
  __syncthreads();
  if (t < 64) {
    float a = bsh[t];
    for (int k = 0; k < 128; k++) a = fmaf(t1[k], Wsh[k * 64 + t], a);
    g2[t] = selu_f(a);
  }
  __syncthreads();
  if (t < 64) {
    float a = bp1[t];
    for (int k = 0; k < 64; k++) a = fmaf(g2[k], Wp1[k * 64 + t], a);
    ha[t] = selu_f(a);
  } else {
    int c = t - 64;
    float a = bv1[c];
    for (int k = 0; k < 64; k++) a = fmaf(g2[k], Wv1[k * 64 + c], a);
    hb[c] = selu_f(a);
  }
  __syncthreads();
  if (t < 64) {
    float a = bp2[t];
    for (int k = 0; k < 64; k++) a = fmaf(ha[k], Wp2[k * 64 + t], a);
    ha2[t] = selu_f(a);
  } else {
    int c = t - 64;
    float a = bv2[c];
    for (int k = 0; k < 64; k++) a = fmaf(hb[k], Wv2[k * 64 + c], a);
    hb2[c] = selu_f(a);
  }
  __syncthreads();
  if (t < 29) {
    float a = bp3[t];
    for (int k = 0; k < 64; k++) a = fmaf(ha2[k], Wp3[k * 29 + t], a);
    logits[t] = a;
  }
  if (t == 127) {
    float a = bv3[0];
    for (int k = 0; k < 64; k++) a = fmaf(hb2[k], Wv3[k], a);
    out[128 + g] = a;
  }
  __syncthreads();
  if (t < 5) {
    const int offs[6] = {0, 7, 11, 17, 21, 29};
    int o0 = offs[t], o1 = offs[t + 1];
    float m = -INFINITY;
    for (int j = o0; j < o1; j++) m = fmaxf(m, logits[j]);
    float Z = 0.f;
    for (int j = o0; j < o1; j++) Z += expf(logits[j] - m);
    float lz = logf(Z);
    int act = ia[t * G_ + g];
    lps[t] = logits[o0 + act] - m - lz;
    float ent = 0.f;
    for (int j = o0; j < o1; j++) {
      float lp_ = logits[j] - m - lz;
      ent -= expf(lp_) * lp_;
    }
    ens[t] = ent;
  }
  __syncthreads();
  if (t == 0) {
    int act = ia[g];
    int sel = min(max(act - 1, 0), 4);
    float flp, fen;
    if (act < 3) { flp = lps[1]; fen = ens[1]; }
    else if (act < 5) { flp = lps[sel]; fen = ens[sel]; }
    else if (act == 5) { flp = lps[1] + lps[4]; fen = ens[1] + ens[4]; }
    else { flp = 0.f; fen = 0.f; }
    out[g] = lps[0] + flp;
    out[G_ + g] = ens[0] + fen;
  }
}

extern "C" void kernel_launch(void* const* d_in, const int* in_sizes, int n_in,
                              void* d_out, int out_size, void* d_ws, size_t ws_size,
                              hipStream_t stream) {
  const float* x = (const float*)d_in[0];
  const int* ei = (const int*)d_in[1];
  const int* batch = (const int*)d_in[2];
  const int* ia = (const int*)d_in[3];
  const float* W1 = (const float*)d_in[4];
  const float* as1 = (const float*)d_in[5];
  const float* ad1 = (const float*)d_in[6];
  const float* b1 = (const float*)d_in[7];
  const float* Wl1 = (const float*)d_in[8];
  const float* bl1 = (const float*)d_in[9];
  const float* W2 = (const float*)d_in[10];
  const float* as2 = (const float*)d_in[11];
  const float* ad2 = (const float*)d_in[12];
  const float* b2 = (const float*)d_in[13];
  const float* Wl2 = (const float*)d_in[14];
  const float* bl2 = (const float*)d_in[15];
  const float* Ws = (const float*)d_in[16];
  const float* bs = (const float*)d_in[17];
  const float* Wsh = (const float*)d_in[18];
  const float* bsh = (const float*)d_in[19];
  const float* Wp1 = (const float*)d_in[20];
  const float* bp1 = (const float*)d_in[21];
  const float* Wp2 = (const float*)d_in[22];
  const float* bp2 = (const float*)d_in[23];
  const float* Wp3 = (const float*)d_in[24];
  const float* bp3 = (const float*)d_in[25];
  const float* Wv1 = (const float*)d_in[26];
  const float* bv1 = (const float*)d_in[27];
  const float* Wv2 = (const float*)d_in[28];
  const float* bv2 = (const float*)d_in[29];
  const float* Wv3 = (const float*)d_in[30];
  const float* bv3 = (const float*)d_in[31];
  float* out = (float*)d_out;

  const int n = in_sizes[0] / IN_;
  const int E = in_sizes[1] / 2;
  const int Mpad = ((n + 255) / 256) * 256;
  const int nb = (n + 1023) / 1024;
  const int* src = ei;
  const int* dst = ei + E;

  char* w = (char*)d_ws;
  size_t cur_off = 0;
  auto alloc = [&](size_t bytes) -> char* {
    char* p = w + cur_off;
    cur_off = (cur_off + bytes + 255) & ~(size_t)255;
    return p;
  };
  int* cnt = (int*)alloc((size_t)n * 4);
  int* off = (int*)alloc((size_t)(n + 1) * 4);
  int* cur = (int*)alloc((size_t)n * 4);
  int* csr = (int*)alloc((size_t)E * 4);
  int* bsum = (int*)alloc((size_t)(nb + 1) * 4);
  unsigned short* xb = (unsigned short*)alloc((size_t)Mpad * 288 * 2);
  unsigned short* h = (unsigned short*)alloc((size_t)Mpad * HC_ * 2);
  float* esed = (float*)alloc((size_t)n * 8 * 4);
  unsigned short* gout = (unsigned short*)alloc((size_t)Mpad * HC_ * 2);
  unsigned short* hs1 = (unsigned short*)alloc((size_t)Mpad * C_ * 2);
  unsigned short* hs2 = (unsigned short*)alloc((size_t)Mpad * C_ * 2);
  unsigned short* W1p = (unsigned short*)alloc((size_t)4 * 9 * 2048 * 2);
  unsigned short* W2p = (unsigned short*)alloc((size_t)4 * 2 * 2048 * 2);
  unsigned short* Wl1p = (unsigned short*)alloc((size_t)1 * 8 * 2048 * 2);
  unsigned short* Wl2p = (unsigned short*)alloc((size_t)1 * 8 * 2048 * 2);
  float* x1x2 = (float*)alloc((size_t)G_ * 256 * 4);
  (void)ws_size;
  (void)n_in;
  (void)out_size;

  // prep: cast x, pack weights, build CSR
  k_cast<<<(Mpad * 288 + 255) / 256, 256, 0, stream>>>(x, xb, n, Mpad);
  k_prep<<<(4 * 9 * 2048 + 255) / 256, 256, 0, stream>>>(W1, W1p, IN_, 9, HC_);
  k_prep<<<(4 * 2 * 2048 + 255) / 256, 256, 0, stream>>>(W2, W2p, C_, 2, HC_);
  k_prep<<<(1 * 8 * 2048 + 255) / 256, 256, 0, stream>>>(Wl1, Wl1p, HC_, 8, C_);
  k_prep<<<(1 * 8 * 2048 + 255) / 256, 256, 0, stream>>>(Wl2, Wl2p, HC_, 8, C_);
  hipMemsetAsync(cnt, 0, (size_t)n * 4, stream);
  int eb = (E + 255) / 256;
  k_count<<<eb, 256, 0, stream>>>(dst, cnt, E);
  k_bsum<<<nb, 256, 0, stream>>>(cnt, bsum, n);
  k_bscan<<<1, 64, 0, stream>>>(bsum, nb, off, n, E);
  k_boff<<<nb, 256, 0, stream>>>(cnt, bsum, off, cur, n);
  k_scatter<<<eb, 256, 0, stream>>>(src, dst, cur, csr, E);

  int gx = Mpad / 256;
  int nwb = (n + 3) / 4;
  // Layer 1
  k_mgemm<0, 9, 1><<<dim3(gx, 4), 256, 9 * 4096, stream>>>(xb, W1p, nullptr, h, 288, HC_);
  k_esed<<<nwb, 256, 0, stream>>>(h, as1, ad1, esed, n);
  k_agg<<<nwb, 256, 0, stream>>>(h, esed, off, csr, b1, gout, n);
  k_mgemm<1, 8, 0><<<dim3(gx, 1), 256, 8 * 4096, stream>>>(gout, Wl1p, bl1, hs1, HC_, C_);
  k_pool<<<G_, 256, 0, stream>>>(hs1, batch, x1x2, n, 0);
  // Layer 2
  k_mgemm<0, 2, 1><<<dim3(gx, 4), 256, 2 * 4096, stream>>>(hs1, W2p, nullptr, h, C_, HC_);
  k_esed<<<nwb, 256, 0, stream>>>(h, as2, ad2, esed, n);
  k_agg<<<nwb, 256, 0, stream>>>(h, esed, off, csr, b2, gout, n);
  k_mgemm<1, 8, 0><<<dim3(gx, 1), 256, 8 * 4096, stream>>>(gout, Wl2p, bl2, hs2, HC_, C_);
  k_pool<<<G_, 256, 0, stream>>>(hs2, batch, x1x2, n, 128);
  // Head
  k_head<<<G_, 128, 0, stream>>>(x1x2, ia, Ws, bs, Wsh, bsh, Wp1, bp1, Wp2, bp2, Wp3, bp3,
                                 Wv1, bv1, Wv2, bv2, Wv3, bv3, out);
}